// Round 3
// baseline (162.347 us; speedup 1.0000x reference)
//
#include <hip/hip_runtime.h>
#include <hip/hip_bf16.h>
#include <stdint.h>

// KAN layer: out[b,o] = sum_{i,k} basis(tanh(x[b,i]))[k] * coeffs[o,i,k]
// GEMM M=8192, N=512, K=4096.  cvt coeffs->Bt bf16 (ws); basis(x)->A (ws);
// gemm(A,Bt)->out.
// R9 post-mortem: in-GEMM basis fusion recomputes each eval 4x (A-stripe
// reused by 4 N-tiles) -> +21us VALU in gemm; basis kernel was already at its
// 80MB HBM floor (13us).  Reverted.
// R10 theory: R7's real limiter is 1 block/CU (128KB LDS, grid 256) -- every
// __syncthreads vmcnt(0) drain stalls the whole CU -- plus 6MB/block LDS
// traffic.  Restructure: 512 blocks x 256 thr (tile 128x64; 4 waves = 2
// K-groups x 2 waveM, wave tile 64x64).  B-fragments come straight from
// global (Bt slice L2-resident, 8 dwordx4/wave/tile prefetched 1 tile ahead;
// barrier drain enforces completion -- no new sync).  LDS = A only:
// 2 grp x dbuf x 16KB = 64KB/block -> 2 independent blocks/CU overlap each
// other's barrier drains.  LDS traffic 6->2 MB/block.  A staging swizzle,
// 1-barrier/iter loop, pair-sum epilogue, C layout all kept from R7.

#define M_TOTAL 8192
#define N_DIM   512
#define K_DIM   4096
#define BM 128
#define BN 64
#define BK 64
#define NT_HALF 32          // K-tiles per K-group (2048/64)
#define GRP_LDS 32768       // per-group arena: 2 buffers x 16KB (A only)

typedef __attribute__((ext_vector_type(8))) short short8;   // 8 x bf16
typedef __attribute__((ext_vector_type(4))) float f32x4;

typedef const __attribute__((address_space(1))) uint32_t ga_u32;
typedef __attribute__((address_space(3))) uint32_t ls_u32;

__device__ __forceinline__ void gload_lds16(const void* g, void* l) {
  // async global->LDS, 16B/lane; LDS dest = wave-uniform base + lane*16
  __builtin_amdgcn_global_load_lds((ga_u32*)(uintptr_t)g,
                                   (ls_u32*)(uint32_t)(uintptr_t)l, 16, 0, 0);
}

__device__ __forceinline__ uint32_t f2bf(float f) {
  uint32_t u = __builtin_bit_cast(uint32_t, f);
  return (u + 0x7FFFu + ((u >> 16) & 1u)) >> 16;
}

// cardinal cubic B-spline on uniform knots h=2/11; t=tanh(x) in (-1,1).
// 8 basis slots as 4xu32 packed bf16: w0..w3 land at slots c-3..c, rest 0.
__device__ __forceinline__ void basis_slots(float xv, uint32_t o[4]) {
  xv = fminf(15.f, fmaxf(-15.f, xv));
  float e  = __expf(2.0f * xv);
  float t  = (e - 1.0f) * __builtin_amdgcn_rcpf(e + 1.0f);
  float uf = (t + 1.0f) * 5.5f;            // /h
  int   c  = (int)uf;  c = c > 10 ? 10 : c;
  float u  = uf - (float)c;
  float u2 = u * u, u3 = u2 * u, om = 1.0f - u;
  float w0 = om * om * om * (1.0f / 6.0f);
  float w1 = (3.0f * u3 - 6.0f * u2 + 4.0f) * (1.0f / 6.0f);
  float w2 = (-3.0f * u3 + 3.0f * u2 + 3.0f * u + 1.0f) * (1.0f / 6.0f);
  float w3 = u3 * (1.0f / 6.0f);
  uint32_t p01 = f2bf(w0) | (f2bf(w1) << 16);
  uint32_t p23 = f2bf(w2) | (f2bf(w3) << 16);
  uint64_t W = (uint64_t)p01 | ((uint64_t)p23 << 32);
  int d = c - 3;                            // slot of w0, in [-3, 7]
  uint64_t lo = (d < 0) ? (W >> ((-d) * 16))
              : ((d < 4) ? (W << (d * 16)) : 0ull);
  uint64_t hi = (d <= 0) ? 0ull
              : ((d < 4) ? (W >> ((4 - d) * 16)) : (W << ((d - 4) * 16)));
  o[0] = (uint32_t)lo; o[1] = (uint32_t)(lo >> 32);
  o[2] = (uint32_t)hi; o[3] = (uint32_t)(hi >> 32);
}

// ---------------- basis kernel: one (b,i) per thread, 16B store --------------
__global__ __launch_bounds__(256) void basis_kernel(const float* __restrict__ x,
                                                    __hip_bfloat16* __restrict__ A,
                                                    int total) {
  int idx = blockIdx.x * 256 + threadIdx.x;
  if (idx >= total) return;
  uint32_t o[4];
  basis_slots(x[idx], o);
  reinterpret_cast<int4*>(A)[idx] = make_int4(o[0], o[1], o[2], o[3]);
}

// ---------------- coeff cast: [512][512][8] fp32 -> bf16 (== B^T[512][4096]) --
__global__ __launch_bounds__(256) void cvt_kernel(const float* __restrict__ c,
                                                  __hip_bfloat16* __restrict__ Bt,
                                                  int total8) {
  int idx = blockIdx.x * 256 + threadIdx.x;
  if (idx >= total8) return;
  const float4* cp = reinterpret_cast<const float4*>(c) + (size_t)idx * 2;
  float4 a = cp[0], b = cp[1];
  union { unsigned short us[8]; int4 v; } pk;
  pk.us[0] = (unsigned short)f2bf(a.x); pk.us[1] = (unsigned short)f2bf(a.y);
  pk.us[2] = (unsigned short)f2bf(a.z); pk.us[3] = (unsigned short)f2bf(a.w);
  pk.us[4] = (unsigned short)f2bf(b.x); pk.us[5] = (unsigned short)f2bf(b.y);
  pk.us[6] = (unsigned short)f2bf(b.z); pk.us[7] = (unsigned short)f2bf(b.w);
  reinterpret_cast<int4*>(Bt)[idx] = pk.v;
}

// ---------------- GEMM: C[m,n] = sum_k A[m,k]*Bt[n,k] ------------------------
// 256 thr = 4 waves: kgrp = wid>>1 (K-half), waveM = wid&1; wave tile 64x64.
__global__ __launch_bounds__(256) void gemm_kernel(
    const __hip_bfloat16* __restrict__ A,   // [8192][4096]
    const __hip_bfloat16* __restrict__ Bt,  // [512][4096]
    float* __restrict__ C) {                // [8192][512]
  __shared__ char lds[2 * GRP_LDS];         // 64 KB -> 2 blocks/CU

  const int tid   = threadIdx.x;
  const int wid   = tid >> 6;               // 0..3
  const int lane  = tid & 63;
  const int quad  = lane >> 4;
  const int l16   = lane & 15;
  const int kgrp  = wid >> 1;               // 0..1: K-half
  const int waveM = wid & 1;                // 0..1: M-half of the 128-row tile
  const int tgg   = tid & 127;              // thread-in-group

  // XCD decode (b&7 = XCD): each XCD owns 8 M-stripes x all 8 N-tiles.
  // A-stripes HBM-streamed once (8 co-resident readers share L2 lines);
  // Bt (4MB) L2-resident per XCD and feeds the B-direct register loads.
  const int b  = blockIdx.x;                // 0..511
  const int s  = b >> 3;                    // 0..63
  const int mt = (b & 7) * 8 + (s >> 3);    // 0..63
  const int nt = s & 7;                     // 0..7
  const int m0 = mt * BM;
  const int n0 = nt * BN;

  char* grp = lds + kgrp * GRP_LDS;

  // A staging: slot s_ -> (row, phys chunk p); source chunk cc = p ^ (row&7).
  // Per group: 128 threads x 8 slots = 1024 x 16B = 16KB A-tile (128 x 64k).
  uint32_t aGlob[8], sOff[8];
#pragma unroll
  for (int t = 0; t < 8; ++t) {
    int s_ = t * 128 + tgg, row = s_ >> 3, p = s_ & 7, cc = p ^ (row & 7);
    sOff[t]  = (uint32_t)s_ * 16u;
    aGlob[t] = (uint32_t)(m0 + row) * K_DIM + (uint32_t)cc * 8u
             + (uint32_t)kgrp * 2048u;
  }

  // A fragment read offsets within the group's buffer (XOR de-swizzle)
  uint32_t aOff[2][4];
#pragma unroll
  for (int kk = 0; kk < 2; ++kk) {
    int c = kk * 4 + quad;
#pragma unroll
    for (int mi = 0; mi < 4; ++mi) {
      int row = waveM * 64 + mi * 16 + l16;
      aOff[kk][mi] = (uint32_t)(row * 8 + (c ^ (row & 7))) * 16u;
    }
  }

  // B fragment global element indices (row-scattered dwordx4, L2-served)
  uint32_t bIdx[2][4];
#pragma unroll
  for (int kk = 0; kk < 2; ++kk)
#pragma unroll
    for (int ni = 0; ni < 4; ++ni) {
      int r = n0 + ni * 16 + l16;
      bIdx[kk][ni] = (uint32_t)r * K_DIM + (uint32_t)kgrp * 2048u
                   + (uint32_t)(kk * 32 + quad * 8);
    }

  f32x4 acc[4][4];
#pragma unroll
  for (int mi = 0; mi < 4; ++mi)
#pragma unroll
    for (int ni = 0; ni < 4; ++ni)
      acc[mi][ni] = (f32x4){0.f, 0.f, 0.f, 0.f};

  // prologue: stage A tile 0; load B frags for tile 0 into registers
  short8 bfA[4], bfB[4];
#pragma unroll
  for (int t = 0; t < 8; ++t)
    gload_lds16(A + aGlob[t], grp + sOff[t]);
#pragma unroll
  for (int ni = 0; ni < 4; ++ni) {
    bfA[ni] = *reinterpret_cast<const short8*>(Bt + bIdx[0][ni]);
    bfB[ni] = *reinterpret_cast<const short8*>(Bt + bIdx[1][ni]);
  }

  for (int it = 0; it < NT_HALF; ++it) {
    char* bufc = grp + (it & 1) * 16384;
    __syncthreads();                        // A(it) staged; B(it) regs landed
    if (it + 1 < NT_HALF) {                 // stage A(it+1) under compute
      char* bufn = grp + ((it + 1) & 1) * 16384;
      uint32_t kt = (uint32_t)(it + 1) * BK;
#pragma unroll
      for (int t = 0; t < 8; ++t)
        gload_lds16(A + aGlob[t] + kt, bufn + sOff[t]);
    }

    // kk=0 with bfA, then refill bfA for it+1 (window: rest of iter + barrier)
    short8 af[4];
#pragma unroll
    for (int mi = 0; mi < 4; ++mi)
      af[mi] = *reinterpret_cast<const short8*>(bufc + aOff[0][mi]);
#pragma unroll
    for (int mi = 0; mi < 4; ++mi)
#pragma unroll
      for (int ni = 0; ni < 4; ++ni)
        acc[mi][ni] = __builtin_amdgcn_mfma_f32_16x16x32_bf16(
            af[mi], bfA[ni], acc[mi][ni], 0, 0, 0);
    if (it + 1 < NT_HALF) {
      uint32_t kt = (uint32_t)(it + 1) * BK;
#pragma unroll
      for (int ni = 0; ni < 4; ++ni)
        bfA[ni] = *reinterpret_cast<const short8*>(Bt + bIdx[0][ni] + kt);
    }

    // kk=1 with bfB, then refill bfB for it+1
#pragma unroll
    for (int mi = 0; mi < 4; ++mi)
      af[mi] = *reinterpret_cast<const short8*>(bufc + aOff[1][mi]);
#pragma unroll
    for (int mi = 0; mi < 4; ++mi)
#pragma unroll
      for (int ni = 0; ni < 4; ++ni)
        acc[mi][ni] = __builtin_amdgcn_mfma_f32_16x16x32_bf16(
            af[mi], bfB[ni], acc[mi][ni], 0, 0, 0);
    if (it + 1 < NT_HALF) {
      uint32_t kt = (uint32_t)(it + 1) * BK;
#pragma unroll
      for (int ni = 0; ni < 4; ++ni)
        bfB[ni] = *reinterpret_cast<const short8*>(Bt + bIdx[1][ni] + kt);
    }
  }

  // split-K pair reduction: group 1 parks partials, group 0 sums + stores
  __syncthreads();
  if (kgrp == 1) {
#pragma unroll
    for (int mi = 0; mi < 4; ++mi)
#pragma unroll
      for (int ni = 0; ni < 4; ++ni) {
        int f = mi * 4 + ni;
        *reinterpret_cast<f32x4*>(lds + waveM * 16384 + f * 1024 + lane * 16) =
            acc[mi][ni];
      }
  }
  __syncthreads();
  if (kgrp == 0) {
#pragma unroll
    for (int mi = 0; mi < 4; ++mi) {
#pragma unroll
      for (int ni = 0; ni < 4; ++ni) {
        int f = mi * 4 + ni;
        f32x4 other = *reinterpret_cast<f32x4*>(
            lds + waveM * 16384 + f * 1024 + lane * 16);
        f32x4 s2 = acc[mi][ni] + other;
        int col = n0 + ni * 16 + l16;
#pragma unroll
        for (int r = 0; r < 4; ++r) {
          int row = m0 + waveM * 64 + mi * 16 + quad * 4 + r;
          C[(size_t)row * N_DIM + col] = s2[r];   // m89/m91 C/D layout
        }
      }
    }
  }
}

extern "C" void kernel_launch(void* const* d_in, const int* in_sizes, int n_in,
                              void* d_out, int out_size, void* d_ws, size_t ws_size,
                              hipStream_t stream) {
  const float* x    = (const float*)d_in[0];   // [8192,512]
  const float* coef = (const float*)d_in[1];   // [512,512,8]
  float* out = (float*)d_out;                  // [8192,512]

  __hip_bfloat16* Bt = (__hip_bfloat16*)d_ws;                       // 4 MB
  __hip_bfloat16* A  = (__hip_bfloat16*)((char*)d_ws + (size_t)4 * 1024 * 1024);
  // A = 64 MB; ws is ~268 MB (observed via harness poison fill), fits.

  const int total8 = N_DIM * K_DIM / 8;        // 262144
  cvt_kernel<<<(total8 + 255) / 256, 256, 0, stream>>>(coef, Bt, total8);

  const int total = M_TOTAL * 512;             // (b,i) pairs
  basis_kernel<<<total / 256, 256, 0, stream>>>(x, A, total);

  gemm_kernel<<<(M_TOTAL / BM) * (N_DIM / BN), 256, 0, stream>>>(A, Bt, out);
}

// Round 4
// 119.329 us; speedup vs baseline: 1.3605x; 1.3605x over previous
//
#include <hip/hip_runtime.h>
#include <hip/hip_bf16.h>
#include <stdint.h>

// KAN layer: out[b,o] = sum_{i,k} basis(tanh(x[b,i]))[k] * coeffs[o,i,k]
// GEMM M=8192, N=512, K=4096.  cvt coeffs->Bt bf16 (ws) ; basis(x)->A (ws) ;
// gemm(A,Bt)->out.
// R10 post-mortem: B-direct-from-global regressed 42->87us (scattered dwordx4
// = 16 L2 segments/instr, refill issued right before the barrier drain).
// Reverted to R7 geometry (proven 42us / 818 TF): 128x128 tile, 8 waves =
// 2 K-groups x (2x2 waves of 64x64), dbuf LDS 128KB, XOR-swizzled
// global_load_lds staging, 1 barrier/iter, split-K pair-sum epilogue.
// R11: single change vs R7 -- MFMA shape 16x16x32 -> 32x32x16.  Same LDS
// read bytes (16 b128/wave/iter), same conflict-free swizzle pattern, but
// matrix-pipe cycles -17% (516 vs 621 cy/SIMD/iter; 2382 vs 2075 TF ceiling)
// and MFMA issue count halved (16 vs 32).  C/D layout per m74/m101:
// col=lane&31, row=(reg&3)+8*(reg>>2)+4*(lane>>5).

#define M_TOTAL 8192
#define N_DIM   512
#define K_DIM   4096
#define BM 128
#define BN 128
#define BK 64
#define NT_HALF 32          // K-tiles per K-group (2048/64)
#define GRP_LDS 65536       // per-group arena: 2 buffers
#define BUF_HALF 32768      // one buffer: A 16KB + B 16KB

typedef __attribute__((ext_vector_type(8))) short short8;    // 8 x bf16
typedef __attribute__((ext_vector_type(4))) float f32x4;
typedef __attribute__((ext_vector_type(16))) float f32x16;

typedef const __attribute__((address_space(1))) uint32_t ga_u32;
typedef __attribute__((address_space(3))) uint32_t ls_u32;

__device__ __forceinline__ void gload_lds16(const void* g, void* l) {
  // async global->LDS, 16B/lane; LDS dest = wave-uniform base + lane*16
  __builtin_amdgcn_global_load_lds((ga_u32*)(uintptr_t)g,
                                   (ls_u32*)(uint32_t)(uintptr_t)l, 16, 0, 0);
}

__device__ __forceinline__ uint32_t f2bf(float f) {
  uint32_t u = __builtin_bit_cast(uint32_t, f);
  return (u + 0x7FFFu + ((u >> 16) & 1u)) >> 16;
}

// cardinal cubic B-spline on uniform knots h=2/11; t=tanh(x) in (-1,1).
// 8 basis slots as 4xu32 packed bf16: w0..w3 land at slots c-3..c, rest 0.
__device__ __forceinline__ void basis_slots(float xv, uint32_t o[4]) {
  xv = fminf(15.f, fmaxf(-15.f, xv));
  float e  = __expf(2.0f * xv);
  float t  = (e - 1.0f) * __builtin_amdgcn_rcpf(e + 1.0f);
  float uf = (t + 1.0f) * 5.5f;            // /h
  int   c  = (int)uf;  c = c > 10 ? 10 : c;
  float u  = uf - (float)c;
  float u2 = u * u, u3 = u2 * u, om = 1.0f - u;
  float w0 = om * om * om * (1.0f / 6.0f);
  float w1 = (3.0f * u3 - 6.0f * u2 + 4.0f) * (1.0f / 6.0f);
  float w2 = (-3.0f * u3 + 3.0f * u2 + 3.0f * u + 1.0f) * (1.0f / 6.0f);
  float w3 = u3 * (1.0f / 6.0f);
  uint32_t p01 = f2bf(w0) | (f2bf(w1) << 16);
  uint32_t p23 = f2bf(w2) | (f2bf(w3) << 16);
  uint64_t W = (uint64_t)p01 | ((uint64_t)p23 << 32);
  int d = c - 3;                            // slot of w0, in [-3, 7]
  uint64_t lo = (d < 0) ? (W >> ((-d) * 16))
              : ((d < 4) ? (W << (d * 16)) : 0ull);
  uint64_t hi = (d <= 0) ? 0ull
              : ((d < 4) ? (W >> ((4 - d) * 16)) : (W << ((d - 4) * 16)));
  o[0] = (uint32_t)lo; o[1] = (uint32_t)(lo >> 32);
  o[2] = (uint32_t)hi; o[3] = (uint32_t)(hi >> 32);
}

// ---------------- basis kernel: one (b,i) per thread, 16B store --------------
__global__ __launch_bounds__(256) void basis_kernel(const float* __restrict__ x,
                                                    __hip_bfloat16* __restrict__ A,
                                                    int total) {
  int idx = blockIdx.x * 256 + threadIdx.x;
  if (idx >= total) return;
  uint32_t o[4];
  basis_slots(x[idx], o);
  reinterpret_cast<int4*>(A)[idx] = make_int4(o[0], o[1], o[2], o[3]);
}

// ---------------- coeff cast: [512][512][8] fp32 -> bf16 (== B^T[512][4096]) --
__global__ __launch_bounds__(256) void cvt_kernel(const float* __restrict__ c,
                                                  __hip_bfloat16* __restrict__ Bt,
                                                  int total8) {
  int idx = blockIdx.x * 256 + threadIdx.x;
  if (idx >= total8) return;
  const float4* cp = reinterpret_cast<const float4*>(c) + (size_t)idx * 2;
  float4 a = cp[0], b = cp[1];
  union { unsigned short us[8]; int4 v; } pk;
  pk.us[0] = (unsigned short)f2bf(a.x); pk.us[1] = (unsigned short)f2bf(a.y);
  pk.us[2] = (unsigned short)f2bf(a.z); pk.us[3] = (unsigned short)f2bf(a.w);
  pk.us[4] = (unsigned short)f2bf(b.x); pk.us[5] = (unsigned short)f2bf(b.y);
  pk.us[6] = (unsigned short)f2bf(b.z); pk.us[7] = (unsigned short)f2bf(b.w);
  reinterpret_cast<int4*>(Bt)[idx] = pk.v;
}

// ---------------- GEMM: C[m,n] = sum_k A[m,k]*Bt[n,k] ------------------------
// 512 thr = 8 waves: kgrp = wid>>2 (K-half), 2x2 waves of 64x64 per group.
// Wave tile 64x64 = 2x2 fragments of 32x32, K-step 16 (4 steps per BK=64).
__global__ __launch_bounds__(512) void gemm_kernel(
    const __hip_bfloat16* __restrict__ A,   // [8192][4096]
    const __hip_bfloat16* __restrict__ Bt,  // [512][4096]
    float* __restrict__ C) {                // [8192][512]
  __shared__ char lds[2 * GRP_LDS];         // 128 KB

  const int tid   = threadIdx.x;
  const int wid   = tid >> 6;               // 0..7
  const int lane  = tid & 63;
  const int l32   = lane & 31;
  const int lh    = lane >> 5;              // 0..1: k-half within fragment
  const int kgrp  = wid >> 2;               // 0..1: K-half
  const int w2    = wid & 3;
  const int waveM = w2 >> 1, waveN = w2 & 1;
  const int tg    = tid & 255;              // thread-in-group

  // XCD decode: each XCD owns 8 M-stripes x all 4 N-tiles; Bt (4MB) stays
  // L2-resident per XCD, A-stripes stream through once.
  const int b  = blockIdx.x;
  const int q  = b >> 3;                    // 0..31
  const int mt = (b & 7) * 8 + (q >> 2);    // 0..63
  const int nt = q & 3;                     // 0..3
  const int m0 = mt * BM;
  const int n0 = nt * BN;

  char* grp = lds + kgrp * GRP_LDS;

  // staging: slot s -> (row, phys chunk p); source chunk cc = p ^ (row&7)
  uint32_t aGlob[4], bGlob[4], sOff[4];
#pragma unroll
  for (int t = 0; t < 4; ++t) {
    int s = t * 256 + tg, row = s >> 3, p = s & 7, cc = p ^ (row & 7);
    sOff[t]  = (uint32_t)s * 16u;
    aGlob[t] = (uint32_t)(m0 + row) * K_DIM + (uint32_t)cc * 8u
             + (uint32_t)kgrp * 2048u;
    bGlob[t] = (uint32_t)(n0 + row) * K_DIM + (uint32_t)cc * 8u
             + (uint32_t)kgrp * 2048u;
  }

  // fragment read offsets (A at +0, B at +16KB).  32x32x16 operand layout:
  // lane holds row = lane&31, k = (lane>>5)*8 + j  ->  chunk c = ks*2 + lh.
  uint32_t aOff[4][2], bOff[4][2];
#pragma unroll
  for (int ks = 0; ks < 4; ++ks) {
    int c = ks * 2 + lh;
#pragma unroll
    for (int mi = 0; mi < 2; ++mi) {
      int row = waveM * 64 + mi * 32 + l32;
      aOff[ks][mi] = (uint32_t)(row * 8 + (c ^ (row & 7))) * 16u;
    }
#pragma unroll
    for (int ni = 0; ni < 2; ++ni) {
      int row = waveN * 64 + ni * 32 + l32;
      bOff[ks][ni] = 16384u + (uint32_t)(row * 8 + (c ^ (row & 7))) * 16u;
    }
  }

  f32x16 acc[2][2];
#pragma unroll
  for (int mi = 0; mi < 2; ++mi)
#pragma unroll
    for (int ni = 0; ni < 2; ++ni)
      acc[mi][ni] = (f32x16){0.f};

  // prologue: stage tile 0 of this K-half into buffer 0
#pragma unroll
  for (int t = 0; t < 4; ++t) {
    gload_lds16(A + aGlob[t], grp + sOff[t]);
    gload_lds16(Bt + bGlob[t], grp + 16384 + sOff[t]);
  }

  for (int it = 0; it < NT_HALF; ++it) {
    const int cur = it & 1;
    char* bufc = grp + cur * BUF_HALF;
    __syncthreads();                        // staging for tile it drained
    if (it + 1 < NT_HALF) {                 // stage it+1 under compute of it
      char* bufn = grp + (1 - cur) * BUF_HALF;
      uint32_t kt = (uint32_t)(it + 1) * BK;
#pragma unroll
      for (int t = 0; t < 4; ++t) {
        gload_lds16(A + aGlob[t] + kt, bufn + sOff[t]);
        gload_lds16(Bt + bGlob[t] + kt, bufn + 16384 + sOff[t]);
      }
    }
#pragma unroll
    for (int ks = 0; ks < 4; ++ks) {
      short8 af0 = *reinterpret_cast<const short8*>(bufc + aOff[ks][0]);
      short8 af1 = *reinterpret_cast<const short8*>(bufc + aOff[ks][1]);
      short8 bf0 = *reinterpret_cast<const short8*>(bufc + bOff[ks][0]);
      short8 bf1 = *reinterpret_cast<const short8*>(bufc + bOff[ks][1]);
      acc[0][0] = __builtin_amdgcn_mfma_f32_32x32x16_bf16(af0, bf0, acc[0][0], 0, 0, 0);
      acc[0][1] = __builtin_amdgcn_mfma_f32_32x32x16_bf16(af0, bf1, acc[0][1], 0, 0, 0);
      acc[1][0] = __builtin_amdgcn_mfma_f32_32x32x16_bf16(af1, bf0, acc[1][0], 0, 0, 0);
      acc[1][1] = __builtin_amdgcn_mfma_f32_32x32x16_bf16(af1, bf1, acc[1][1], 0, 0, 0);
    }
  }

  // split-K pair reduction: group 1 parks partials, group 0 sums + stores
  __syncthreads();
  if (kgrp == 1) {
#pragma unroll
    for (int mi = 0; mi < 2; ++mi)
#pragma unroll
      for (int ni = 0; ni < 2; ++ni) {
        int f = mi * 2 + ni;
        *reinterpret_cast<f32x16*>(lds + w2 * 16384 + f * 4096 + lane * 64) =
            acc[mi][ni];
      }
  }
  __syncthreads();
  if (kgrp == 0) {
#pragma unroll
    for (int mi = 0; mi < 2; ++mi) {
#pragma unroll
      for (int ni = 0; ni < 2; ++ni) {
        int f = mi * 2 + ni;
        f32x16 other = *reinterpret_cast<f32x16*>(
            lds + w2 * 16384 + f * 4096 + lane * 64);
        f32x16 s = acc[mi][ni] + other;
        int col   = n0 + waveN * 64 + ni * 32 + l32;
        int rbase = m0 + waveM * 64 + mi * 32 + lh * 4;
#pragma unroll
        for (int r = 0; r < 16; ++r) {
          int row = rbase + (r & 3) + 8 * (r >> 2);   // m74/m101 C/D layout
          C[(size_t)row * N_DIM + col] = s[r];
        }
      }
    }
  }
}

extern "C" void kernel_launch(void* const* d_in, const int* in_sizes, int n_in,
                              void* d_out, int out_size, void* d_ws, size_t ws_size,
                              hipStream_t stream) {
  const float* x    = (const float*)d_in[0];   // [8192,512]
  const float* coef = (const float*)d_in[1];   // [512,512,8]
  float* out = (float*)d_out;                  // [8192,512]

  __hip_bfloat16* Bt = (__hip_bfloat16*)d_ws;                       // 4 MB
  __hip_bfloat16* A  = (__hip_bfloat16*)((char*)d_ws + (size_t)4 * 1024 * 1024);
  // A = 64 MB; ws is ~268 MB (observed via harness poison fill), fits.

  const int total8 = N_DIM * K_DIM / 8;        // 262144
  cvt_kernel<<<(total8 + 255) / 256, 256, 0, stream>>>(coef, Bt, total8);

  const int total = M_TOTAL * 512;             // (b,i) pairs
  basis_kernel<<<total / 256, 256, 0, stream>>>(x, A, total);

  gemm_kernel<<<(M_TOTAL / BM) * (N_DIM / BN), 512, 0, stream>>>(A, Bt, out);
}